// Round 9
// baseline (552.215 us; speedup 1.0000x reference)
//
#include <hip/hip_runtime.h>
#include <hip/hip_bf16.h>
#include <math.h>

#define HID 64
#define HEADS 4
#define LAYERS 4
#define NRBF 20
#define NG 256
#define CB 512     // HID*8 floats per node
#define HSTRIDE 68 // padded channel stride in LDS hAl (bf16 elems)
#define CAPB 128   // per-dst edge bucket capacity (Poisson(16); P(deg>=128)~0)
#define TABN 8192  // edge-MLP distance table: [0,16], step 1/512

typedef __attribute__((ext_vector_type(8))) short short8;
typedef __attribute__((ext_vector_type(4))) float floatx4;

__device__ __forceinline__ int gradeOf(int b){ return (b==0)?0:((b<4)?1:((b<7)?2:3)); }
__device__ __forceinline__ unsigned short f2bf(float f){
    __hip_bfloat16 h = __float2bfloat16(f);
    return *(unsigned short*)&h;
}
__device__ __forceinline__ float bflo(int u){ return __uint_as_float(((unsigned)u)<<16); }
__device__ __forceinline__ float bfhi(int u){ return __uint_as_float(((unsigned)u)&0xFFFF0000u); }

struct P {
    const float *pos; const int *zidx; const int *ei; const int *batch;
    const float *atom_w, *inproj_w, *inproj_b, *ew1, *eb1, *ew2, *eb2;
    const float *proj_w, *proj_b, *a_src, *a_dst, *w_src, *w_dst;
    const float *ln_a, *silu_a, *silu_b, *ppw, *ppb, *pw1, *pb1, *pw2, *pb2;
    float *out;
    int *counts; float *possum; float *pcnt; float *gbuf;
    int *bucket; float *esc; float *tab;
    float *inwT; unsigned short *WTbf; float *ppw0T; float *w1T; float *sbf;
    float *h; unsigned short *hA;
    unsigned short *zA; unsigned short *zB;
    float *ssA; float *sdA; float *ssB; float *sdB;
    int N, E, Mtiles;
};

// ---------------- edge-MLP distance table: one wave per entry, lane = hidden channel ----------------
__global__ __launch_bounds__(256) void tab_kernel(P p){
    int wv = threadIdx.x>>6, lane = threadIdx.x&63;
    int i = blockIdx.x*4 + wv;
    if (i > TABN) return;
    float d = (float)i * (16.0f/TABN);
    float t0 = d * (19.0f/10.0f);
    float hv = p.eb1[lane];
    #pragma unroll
    for (int k=0;k<NRBF;k++){
        float a = t0 - (float)k;
        hv += __expf(-0.5f*a*a) * p.ew1[lane*NRBF+k];
    }
    float act = hv/(1.0f+__expf(-hv));
    float p0 = act*p.ew2[0*HID+lane];
    float p1 = act*p.ew2[1*HID+lane];
    float p2 = act*p.ew2[2*HID+lane];
    float p3 = act*p.ew2[3*HID+lane];
    #pragma unroll
    for (int off=1; off<64; off<<=1){
        p0 += __shfl_xor(p0,off,64);
        p1 += __shfl_xor(p1,off,64);
        p2 += __shfl_xor(p2,off,64);
        p3 += __shfl_xor(p3,off,64);
    }
    if (lane==0){
        *(float4*)&p.tab[(size_t)i*4] = make_float4(p0+p.eb2[0], p1+p.eb2[1],
                                                    p2+p.eb2[2], p3+p.eb2[3]);
    }
}

// ---------------- pre: prep | node_stats | edge (table lerp) + bucket fill ----------------
__global__ __launch_bounds__(256) void pre_kernel(P p){
    const int PREP_TOTAL = LAYERS*4*64*64 + 65*HID + 2*HID*HID + 2*LAYERS*HEADS; // 77920
    const int CP = (PREP_TOTAL+255)/256;
    const int CN = (p.N+255)/256;
    int bid = blockIdx.x, t = threadIdx.x;
    if (bid < CP){
        int idx = bid*256 + t;
        const int szW = LAYERS*4*64*64;
        const int e1 = szW + 65*HID;
        const int e2 = e1 + HID*HID;
        const int e3 = e2 + HID*HID;
        if (idx < szW){
            p.WTbf[idx] = f2bf(p.proj_w[idx]);
        } else if (idx < e1){
            int r = idx - szW; int i = r/HID, o = r%HID;
            p.inwT[r] = p.inproj_w[o*65 + i];
        } else if (idx < e2){
            int r = idx - e1; int i = r/HID, o = r%HID;
            p.ppw0T[r] = p.ppw[o*HID + i];
        } else if (idx < e3){
            int r = idx - e2; int i = r/HID, o = r%HID;
            p.w1T[r] = p.pw1[o*HID + i];
        } else if (idx < e3 + 2*LAYERS*HEADS){
            int r = idx - e3;
            int hh = r & 3; int type = (r>>2)&1; int l = r>>3;
            const float* a = type ? p.a_dst : p.a_src;
            const float* w = type ? p.w_dst : p.w_src;
            float wh = w[l*16 + hh*4 + 0];
            float s = 0.f;
            for (int c=0;c<16;c++)
                s += a[l*512 + (hh*16+c)*8 + 0] * wh * p.proj_b[l*64 + hh*16 + c];
            p.sbf[r] = s;
        }
    } else if (bid < CP+CN){
        int n = (bid-CP)*256 + t;
        if (n < p.N){
            int g = p.batch[n];
            atomicAdd(&p.possum[g*3+0], p.pos[n*3+0]);
            atomicAdd(&p.possum[g*3+1], p.pos[n*3+1]);
            atomicAdd(&p.possum[g*3+2], p.pos[n*3+2]);
            atomicAdd(&p.pcnt[g], 1.0f);
        }
    } else {
        int e = (bid-CP-CN)*256 + t;
        if (e >= p.E) return;
        int s = p.ei[e], d = p.ei[p.E+e];
        float dx = p.pos[s*3+0]-p.pos[d*3+0];
        float dy = p.pos[s*3+1]-p.pos[d*3+1];
        float dz = p.pos[s*3+2]-p.pos[d*3+2];
        float dist = sqrtf(dx*dx+dy*dy+dz*dz);
        // edge MLP via distance table + lerp (f is 1-D smooth; error ~1e-5)
        float idxf = fminf(dist * ((float)TABN/16.0f), (float)(TABN-1));
        int i0 = (int)idxf;
        float fr = idxf - (float)i0;
        float4 f0 = *(const float4*)&p.tab[(size_t)i0*4];
        float4 f1 = *(const float4*)&p.tab[(size_t)(i0+1)*4];
        float4 ev = make_float4(f0.x + (f1.x-f0.x)*fr, f0.y + (f1.y-f0.y)*fr,
                                f0.z + (f1.z-f0.z)*fr, f0.w + (f1.w-f0.w)*fr);
        *(float4*)&p.esc[(size_t)e*4] = ev;
        int slot = atomicAdd(&p.counts[d],1);
        if (slot < CAPB) p.bucket[(size_t)d*CAPB + slot] = e;
    }
}

// ---------------- proj math body (A-frags supplied by caller) ----------------
__device__ __forceinline__ void proj_core(const P& p, int pl, int n0, int nt, int lane,
        const short8* afr,
        unsigned short* zout, float* ssout, float* sdout){
    const unsigned short* WTl = p.WTbf + (size_t)pl*4*64*64;
    const float* pbl = p.proj_b + pl*HID;
    const float* a_src_l = p.a_src + pl*512;
    const float* a_dst_l = p.a_dst + pl*512;
    const float* w_src_l = p.w_src + pl*16;
    const float* w_dst_l = p.w_dst + pl*16;
    const float* sb_l = p.sbf + pl*8;
    int m = lane&15, quad = lane>>4;
    int o = nt*16 + m;
    float cs[4][2][4];
    float pss[4], psd[4];
    #pragma unroll
    for (int r=0;r<4;r++){ pss[r]=0.f; psd[r]=0.f; }
    #pragma unroll
    for (int bp=0; bp<4; bp++){
        const int b0 = 2*bp, b1 = b0+1;
        const int g0 = gradeOf(b0), g1 = gradeOf(b1);
        const short8 w00 = *(const short8*)(WTl + (g0*64 + o)*64 + quad*8);
        const short8 w01 = *(const short8*)(WTl + (g0*64 + o)*64 + 32 + quad*8);
        short8 w10, w11;
        if (g1==g0){ w10 = w00; w11 = w01; }
        else {
            w10 = *(const short8*)(WTl + (g1*64 + o)*64 + quad*8);
            w11 = *(const short8*)(WTl + (g1*64 + o)*64 + 32 + quad*8);
        }
        floatx4 c0 = {0.f,0.f,0.f,0.f}, c1 = {0.f,0.f,0.f,0.f};
        c0 = __builtin_amdgcn_mfma_f32_16x16x32_bf16(afr[4*bp+0], w00, c0, 0,0,0);
        c0 = __builtin_amdgcn_mfma_f32_16x16x32_bf16(afr[4*bp+1], w01, c0, 0,0,0);
        c1 = __builtin_amdgcn_mfma_f32_16x16x32_bf16(afr[4*bp+2], w10, c1, 0,0,0);
        c1 = __builtin_amdgcn_mfma_f32_16x16x32_bf16(afr[4*bp+3], w11, c1, 0,0,0);
        float as0 = a_src_l[o*8+b0]*w_src_l[nt*4+g0];
        float as1 = a_src_l[o*8+b1]*w_src_l[nt*4+g1];
        float ad0 = a_dst_l[o*8+b0]*w_dst_l[nt*4+g0];
        float ad1 = a_dst_l[o*8+b1]*w_dst_l[nt*4+g1];
        float bias0 = (bp==0) ? pbl[o] : 0.0f;
        #pragma unroll
        for (int r=0;r<4;r++){
            float v0 = c0[r], v1 = c1[r];
            pss[r] += v0*as0 + v1*as1;
            psd[r] += v0*ad0 + v1*ad1;
            cs[bp][0][r] = v0 + bias0;
            cs[bp][1][r] = v1;
        }
    }
    #pragma unroll
    for (int r=0;r<4;r++){
        int nn = n0 + quad*4 + r;
        if (nn < p.N){
            unsigned short pk[8];
            #pragma unroll
            for (int bp=0;bp<4;bp++){
                pk[2*bp]   = f2bf(cs[bp][0][r]);
                pk[2*bp+1] = f2bf(cs[bp][1][r]);
            }
            *(int4*)(zout + (size_t)nn*CB + o*8) = *(int4*)pk;
        }
    }
    #pragma unroll
    for (int r=0;r<4;r++){
        float vs = pss[r], vd = psd[r];
        #pragma unroll
        for (int off=1; off<16; off<<=1){
            vs += __shfl_xor(vs, off, 64);
            vd += __shfl_xor(vd, off, 64);
        }
        int nn = n0 + quad*4 + r;
        if (m==0 && nn<p.N){
            ssout[nn*4+nt] = vs + sb_l[nt];
            sdout[nn*4+nt] = vd + sb_l[4+nt];
        }
    }
}

// ---------------- embed + proj_0 (A from LDS) ----------------
__global__ __launch_bounds__(256) void embedproj_kernel(P p){
    __shared__ unsigned short hAl[8*16*HSTRIDE];
    int t = threadIdx.x, wv = t>>6, lane = t&63;
    int n0 = blockIdx.x*16;
    for (int k=0;k<4;k++){
        int m = wv*4 + k;
        int n = n0 + m;
        if (n < p.N){
            int zn = p.zidx[n];                    // wave-uniform
            const float* ar = p.atom_w + (size_t)zn*HID;  // uniform base -> s_load
            float acc = p.inproj_b[lane];
            for (int i=0;i<HID;i++) acc += ar[i] * p.inwT[i*HID + lane];
            int g = p.batch[n];
            float cm = p.pcnt[g]; cm = cm>1.0f?cm:1.0f;
            float px = p.pos[n*3+0]-p.possum[g*3+0]/cm;
            float py = p.pos[n*3+1]-p.possum[g*3+1]/cm;
            float pz = p.pos[n*3+2]-p.possum[g*3+2]/cm;
            float wvv = p.inwT[HID*HID + lane];
            float4* hp = (float4*)&p.h[(size_t)n*CB + lane*8];
            hp[0] = make_float4(acc, wvv*px, wvv*py, wvv*pz);
            hp[1] = make_float4(0.f,0.f,0.f,0.f);
            float vals[8] = {acc, wvv*px, wvv*py, wvv*pz, 0.f,0.f,0.f,0.f};
            #pragma unroll
            for (int b=0;b<8;b++) hAl[(b*16+m)*HSTRIDE + lane] = f2bf(vals[b]);
        } else {
            #pragma unroll
            for (int b=0;b<8;b++) hAl[(b*16+m)*HSTRIDE + lane] = 0;
        }
    }
    __syncthreads();
    int m = lane&15, quad = lane>>4;
    short8 afr[16];
    #pragma unroll
    for (int bp=0;bp<4;bp++){
        int b0=2*bp, b1=b0+1;
        afr[4*bp+0] = *(const short8*)(hAl + (b0*16+m)*HSTRIDE + quad*8);
        afr[4*bp+1] = *(const short8*)(hAl + (b0*16+m)*HSTRIDE + 32 + quad*8);
        afr[4*bp+2] = *(const short8*)(hAl + (b1*16+m)*HSTRIDE + quad*8);
        afr[4*bp+3] = *(const short8*)(hAl + (b1*16+m)*HSTRIDE + 32 + quad*8);
    }
    proj_core(p, 0, n0, wv, lane, afr, p.zA, p.ssA, p.sdA);
}

// ---------------- standalone proj_l (A from global hA), 4 waves = 4 o-tiles ----------------
__global__ __launch_bounds__(256) void proj_kernel(P p, int pl,
        unsigned short* zout, float* ssout, float* sdout){
    int t = threadIdx.x, wv = t>>6, lane = t&63;
    int n0 = blockIdx.x*16;
    int m = lane&15, quad = lane>>4;
    int nm = min(n0+m, p.N-1);
    const int N = p.N;
    short8 afr[16];
    #pragma unroll
    for (int bp=0;bp<4;bp++){
        int b0=2*bp, b1=b0+1;
        afr[4*bp+0] = *(const short8*)(p.hA + ((size_t)b0*N + nm)*HID + quad*8);
        afr[4*bp+1] = *(const short8*)(p.hA + ((size_t)b0*N + nm)*HID + 32 + quad*8);
        afr[4*bp+2] = *(const short8*)(p.hA + ((size_t)b1*N + nm)*HID + quad*8);
        afr[4*bp+3] = *(const short8*)(p.hA + ((size_t)b1*N + nm)*HID + 32 + quad*8);
    }
    proj_core(p, pl, n0, wv, lane, afr, zout, ssout, sdout);
}

// ---------------- wave-per-node agg (bucket edges) + mvSiLU + residual + LN (+prepool) ----------------
__global__ __launch_bounds__(256) void agg_kernel(P p, int l,
        const unsigned short* __restrict__ zin, const float* __restrict__ ssin,
        const float* __restrict__ sdin, int last){
    __shared__ float lw[4][256];
    int wv = threadIdx.x>>6, lane = threadIdx.x&63;
    float* lwv = lw[wv];
    int n = blockIdx.x*4 + wv;
    if (n >= p.N) return;
    const float* silu_a_l = p.silu_a + l*HID*4;
    const float* silu_b_l = p.silu_b + l*HID*4;
    const float* ln_a_l   = p.ln_a + l*HID;
    int deg = min(p.counts[n], CAPB);
    const int* buck = p.bucket + (size_t)n*CAPB;
    float4 sdl = *(const float4*)&sdin[n*4];
    int h_id = lane>>4;
    float m0=-1e30f,m1=-1e30f,m2=-1e30f,m3=-1e30f;
    float acc[8];
    #pragma unroll
    for (int k=0;k<8;k++) acc[k]=0.f;
    float dn = 0.f;
    for (int c0=0; c0<deg; c0+=64){
        int cnt = min(64, deg-c0);
        int s = 0;
        float l0=-1e30f,l1=-1e30f,l2=-1e30f,l3=-1e30f;
        if (lane < cnt){
            int e = buck[c0+lane]; s = p.ei[e];
            float4 sv = *(const float4*)&ssin[s*4];
            float4 evv = *(const float4*)&p.esc[(size_t)e*4];
            l0 = sv.x+sdl.x+evv.x; l0=(l0>=0.f)?l0:0.2f*l0;
            l1 = sv.y+sdl.y+evv.y; l1=(l1>=0.f)?l1:0.2f*l1;
            l2 = sv.z+sdl.z+evv.z; l2=(l2>=0.f)?l2:0.2f*l2;
            l3 = sv.w+sdl.w+evv.w; l3=(l3>=0.f)?l3:0.2f*l3;
        }
        float c0m=l0,c1m=l1,c2m=l2,c3m=l3;
        #pragma unroll
        for (int off=1; off<64; off<<=1){
            c0m=fmaxf(c0m,__shfl_xor(c0m,off,64));
            c1m=fmaxf(c1m,__shfl_xor(c1m,off,64));
            c2m=fmaxf(c2m,__shfl_xor(c2m,off,64));
            c3m=fmaxf(c3m,__shfl_xor(c3m,off,64));
        }
        float nm0=fmaxf(m0,c0m), nm1=fmaxf(m1,c1m), nm2=fmaxf(m2,c2m), nm3=fmaxf(m3,c3m);
        float mo  = (h_id==0)?m0:((h_id==1)?m1:((h_id==2)?m2:m3));
        float nmo = (h_id==0)?nm0:((h_id==1)?nm1:((h_id==2)?nm2:nm3));
        float sc = __expf(mo-nmo);
        #pragma unroll
        for (int k=0;k<8;k++) acc[k]*=sc;
        dn *= sc;
        m0=nm0; m1=nm1; m2=nm2; m3=nm3;
        float4 wquad = make_float4(__expf(l0-nm0),__expf(l1-nm1),__expf(l2-nm2),__expf(l3-nm3));
        *(float4*)&lwv[lane*4] = wquad;
        int rc = (cnt+3)&~3;
        for (int j=0;j<rc;j+=4){
            int s0 = __shfl(s, j+0), s1 = __shfl(s, j+1);
            int s2 = __shfl(s, j+2), s3 = __shfl(s, j+3);
            const int4 zv0 = *((const int4*)(zin + (size_t)s0*CB) + lane);
            const int4 zv1 = *((const int4*)(zin + (size_t)s1*CB) + lane);
            const int4 zv2 = *((const int4*)(zin + (size_t)s2*CB) + lane);
            const int4 zv3 = *((const int4*)(zin + (size_t)s3*CB) + lane);
            float w0 = lwv[(j+0)*4 + h_id], w1 = lwv[(j+1)*4 + h_id];
            float w2 = lwv[(j+2)*4 + h_id], w3 = lwv[(j+3)*4 + h_id];
            acc[0] += w0*bflo(zv0.x); acc[1] += w0*bfhi(zv0.x);
            acc[2] += w0*bflo(zv0.y); acc[3] += w0*bfhi(zv0.y);
            acc[4] += w0*bflo(zv0.z); acc[5] += w0*bfhi(zv0.z);
            acc[6] += w0*bflo(zv0.w); acc[7] += w0*bfhi(zv0.w);
            acc[0] += w1*bflo(zv1.x); acc[1] += w1*bfhi(zv1.x);
            acc[2] += w1*bflo(zv1.y); acc[3] += w1*bfhi(zv1.y);
            acc[4] += w1*bflo(zv1.z); acc[5] += w1*bfhi(zv1.z);
            acc[6] += w1*bflo(zv1.w); acc[7] += w1*bfhi(zv1.w);
            acc[0] += w2*bflo(zv2.x); acc[1] += w2*bfhi(zv2.x);
            acc[2] += w2*bflo(zv2.y); acc[3] += w2*bfhi(zv2.y);
            acc[4] += w2*bflo(zv2.z); acc[5] += w2*bfhi(zv2.z);
            acc[6] += w2*bflo(zv2.w); acc[7] += w2*bfhi(zv2.w);
            acc[0] += w3*bflo(zv3.x); acc[1] += w3*bfhi(zv3.x);
            acc[2] += w3*bflo(zv3.y); acc[3] += w3*bfhi(zv3.y);
            acc[4] += w3*bflo(zv3.z); acc[5] += w3*bfhi(zv3.z);
            acc[6] += w3*bflo(zv3.w); acc[7] += w3*bfhi(zv3.w);
            dn += w0+w1+w2+w3;
        }
    }
    float inv = 1.0f/(dn + 1e-16f);
    float x[8];
    #pragma unroll
    for (int k=0;k<8;k++) x[k] = acc[k]*inv;
    float4 sa = *(const float4*)&silu_a_l[lane*4];
    float4 sb = *(const float4*)&silu_b_l[lane*4];
    float n1 = x[1]*x[1]+x[2]*x[2]+x[3]*x[3];
    float n2 = x[4]*x[4]+x[5]*x[5]+x[6]*x[6];
    float n3 = x[7]*x[7];
    float g0 = 1.0f/(1.0f+__expf(-(sa.x*x[0]+sb.x)));
    float g1 = 1.0f/(1.0f+__expf(-(sa.y*n1+sb.y)));
    float g2 = 1.0f/(1.0f+__expf(-(sa.z*n2+sb.z)));
    float g3 = 1.0f/(1.0f+__expf(-(sa.w*n3+sb.w)));
    float4 r0 = *(const float4*)&p.h[(size_t)n*CB + lane*8];
    float4 r1 = *(const float4*)&p.h[(size_t)n*CB + lane*8 + 4];
    float val[8];
    val[0]=g0*x[0]+r0.x; val[1]=g1*x[1]+r0.y; val[2]=g1*x[2]+r0.z; val[3]=g1*x[3]+r0.w;
    val[4]=g2*x[4]+r1.x; val[5]=g2*x[5]+r1.y; val[6]=g2*x[6]+r1.z; val[7]=g3*x[7]+r1.w;
    float ss=0.f;
    #pragma unroll
    for (int k=0;k<8;k++) ss += val[k]*val[k];
    float nr = sqrtf(ss);
    #pragma unroll
    for (int off=1; off<64; off<<=1) nr += __shfl_xor(nr, off, 64);
    float mean = nr*(1.0f/64.0f) + 1e-6f;
    float scale = ln_a_l[lane]/mean;
    float outv[8];
    #pragma unroll
    for (int k=0;k<8;k++) outv[k] = scale*val[k];
    if (!last){
        *(float4*)&p.h[(size_t)n*CB + lane*8]     = make_float4(outv[0],outv[1],outv[2],outv[3]);
        *(float4*)&p.h[(size_t)n*CB + lane*8 + 4] = make_float4(outv[4],outv[5],outv[6],outv[7]);
        #pragma unroll
        for (int b=0;b<8;b++) p.hA[((size_t)b*p.N + n)*HID + lane] = f2bf(outv[b]);
    } else {
        float x0 = outv[0];
        float accp = p.ppb[lane];
        for (int i=0;i<HID;i++) accp += __shfl(x0, i, 64) * p.ppw0T[i*HID + lane];
        atomicAdd(&p.gbuf[p.batch[n]*HID + lane], accp);
    }
}

// ---------------- final readout ----------------
__global__ void final_kernel(P p){
    int gid = blockIdx.x; int o = threadIdx.x;  // 64 threads = 1 wave
    float gv = p.gbuf[gid*HID + o];
    float a = p.pb1[o];
    for (int i=0;i<HID;i++) a += __shfl(gv, i, 64) * p.w1T[i*HID + o];
    float act = a/(1.0f+__expf(-a));
    float pv = act * p.pw2[o];
    #pragma unroll
    for (int off=1; off<64; off<<=1) pv += __shfl_xor(pv, off, 64);
    if (o==0) p.out[gid] = pv + p.pb2[0];
}

extern "C" void kernel_launch(void* const* d_in, const int* in_sizes, int n_in,
                              void* d_out, int out_size, void* d_ws, size_t ws_size,
                              hipStream_t stream) {
    P p;
    p.pos      = (const float*)d_in[0];
    p.zidx     = (const int*)  d_in[1];
    p.ei       = (const int*)  d_in[2];
    p.batch    = (const int*)  d_in[3];
    p.atom_w   = (const float*)d_in[4];
    p.inproj_w = (const float*)d_in[5];
    p.inproj_b = (const float*)d_in[6];
    p.ew1      = (const float*)d_in[7];
    p.eb1      = (const float*)d_in[8];
    p.ew2      = (const float*)d_in[9];
    p.eb2      = (const float*)d_in[10];
    p.proj_w   = (const float*)d_in[11];
    p.proj_b   = (const float*)d_in[12];
    p.a_src    = (const float*)d_in[13];
    p.a_dst    = (const float*)d_in[14];
    p.w_src    = (const float*)d_in[15];
    p.w_dst    = (const float*)d_in[16];
    p.ln_a     = (const float*)d_in[17];
    p.silu_a   = (const float*)d_in[18];
    p.silu_b   = (const float*)d_in[19];
    p.ppw      = (const float*)d_in[20];
    p.ppb      = (const float*)d_in[21];
    p.pw1      = (const float*)d_in[22];
    p.pb1      = (const float*)d_in[23];
    p.pw2      = (const float*)d_in[24];
    p.pb2      = (const float*)d_in[25];
    p.out = (float*)d_out;

    const int N = in_sizes[0]/3;
    const int E = in_sizes[2]/2;
    p.N = N; p.E = E; p.Mtiles = (N+15)/16;

    float* wsf = (float*)d_ws;
    size_t off = 0;
    auto alloc = [&](size_t nelem){ size_t r = off; off += (nelem + 63) & ~(size_t)63; return r; };
    size_t o_counts = alloc(N);          // int
    size_t o_possum = alloc(NG*3);
    size_t o_pcnt   = alloc(NG);
    size_t o_g      = alloc(NG*HID);
    size_t zero_end = off;
    size_t o_bucket = alloc((size_t)N*CAPB);   // int
    size_t o_esc    = alloc((size_t)E*4);
    size_t o_tab    = alloc((size_t)(TABN+2)*4);
    size_t o_ssA    = alloc((size_t)N*4);
    size_t o_sdA    = alloc((size_t)N*4);
    size_t o_ssB    = alloc((size_t)N*4);
    size_t o_sdB    = alloc((size_t)N*4);
    size_t o_inwT   = alloc(65*HID);
    size_t o_WTbf   = alloc((size_t)LAYERS*4*64*64/2);   // ushort
    size_t o_ppw0T  = alloc(HID*HID);
    size_t o_w1T    = alloc(HID*HID);
    size_t o_sbf    = alloc(2*LAYERS*HEADS);
    size_t o_h      = alloc((size_t)N*CB);
    size_t o_hA     = alloc((size_t)N*CB/2);             // ushort
    size_t o_zA     = alloc((size_t)N*CB/2);             // ushort
    size_t o_zB     = alloc((size_t)N*CB/2);             // ushort

    p.counts = (int*)(wsf + o_counts);
    p.possum = wsf + o_possum;
    p.pcnt   = wsf + o_pcnt;
    p.gbuf   = wsf + o_g;
    p.bucket = (int*)(wsf + o_bucket);
    p.esc    = wsf + o_esc;
    p.tab    = wsf + o_tab;
    p.ssA    = wsf + o_ssA;
    p.sdA    = wsf + o_sdA;
    p.ssB    = wsf + o_ssB;
    p.sdB    = wsf + o_sdB;
    p.inwT   = wsf + o_inwT;
    p.WTbf   = (unsigned short*)(wsf + o_WTbf);
    p.ppw0T  = wsf + o_ppw0T;
    p.w1T    = wsf + o_w1T;
    p.sbf    = wsf + o_sbf;
    p.h      = wsf + o_h;
    p.hA     = (unsigned short*)(wsf + o_hA);
    p.zA     = (unsigned short*)(wsf + o_zA);
    p.zB     = (unsigned short*)(wsf + o_zB);

    hipMemsetAsync(wsf, 0, zero_end*sizeof(float), stream);

    const int PREP_TOTAL = LAYERS*4*64*64 + 65*HID + 2*HID*HID + 2*LAYERS*HEADS;
    const int CP = (PREP_TOTAL+255)/256;
    const int CN = (N+255)/256;
    const int CE = (E+255)/256;

    tab_kernel<<<(TABN+1+3)/4, 256, 0, stream>>>(p);
    pre_kernel<<<CP+CN+CE, 256, 0, stream>>>(p);
    embedproj_kernel<<<p.Mtiles, 256, 0, stream>>>(p);          // -> zA, ssA, sdA

    agg_kernel<<<(N+3)/4, 256, 0, stream>>>(p, 0, p.zA, p.ssA, p.sdA, 0);   // -> h, hA
    proj_kernel<<<p.Mtiles, 256, 0, stream>>>(p, 1, p.zB, p.ssB, p.sdB);
    agg_kernel<<<(N+3)/4, 256, 0, stream>>>(p, 1, p.zB, p.ssB, p.sdB, 0);
    proj_kernel<<<p.Mtiles, 256, 0, stream>>>(p, 2, p.zA, p.ssA, p.sdA);
    agg_kernel<<<(N+3)/4, 256, 0, stream>>>(p, 2, p.zA, p.ssA, p.sdA, 0);
    proj_kernel<<<p.Mtiles, 256, 0, stream>>>(p, 3, p.zB, p.ssB, p.sdB);
    agg_kernel<<<(N+3)/4, 256, 0, stream>>>(p, 3, p.zB, p.ssB, p.sdB, 1);   // + prepool

    final_kernel<<<NG, 64, 0, stream>>>(p);
}

// Round 10
// 549.086 us; speedup vs baseline: 1.0057x; 1.0057x over previous
//
#include <hip/hip_runtime.h>
#include <hip/hip_bf16.h>
#include <math.h>

#define HID 64
#define HEADS 4
#define LAYERS 4
#define NRBF 20
#define NG 256
#define CB 512     // HID*8 floats per node
#define HSTRIDE 68 // padded channel stride in LDS (bf16 elems)
#define CAPB 128   // per-dst edge bucket capacity
#define TABN 8192  // edge-MLP distance table: [0,16], step 1/512

typedef __attribute__((ext_vector_type(8))) short short8;
typedef __attribute__((ext_vector_type(4))) float floatx4;

__device__ __forceinline__ int gradeOf(int b){ return (b==0)?0:((b<4)?1:((b<7)?2:3)); }
__device__ __forceinline__ unsigned short f2bf(float f){
    __hip_bfloat16 h = __float2bfloat16(f);
    return *(unsigned short*)&h;
}
__device__ __forceinline__ float bflo(int u){ return __uint_as_float(((unsigned)u)<<16); }
__device__ __forceinline__ float bfhi(int u){ return __uint_as_float(((unsigned)u)&0xFFFF0000u); }

struct P {
    const float *pos; const int *zidx; const int *ei; const int *batch;
    const float *atom_w, *inproj_w, *inproj_b, *ew1, *eb1, *ew2, *eb2;
    const float *proj_w, *proj_b, *a_src, *a_dst, *w_src, *w_dst;
    const float *ln_a, *silu_a, *silu_b, *ppw, *ppb, *pw1, *pb1, *pw2, *pb2;
    float *out;
    int *counts; float *possum; float *pcnt; float *gbuf;
    int *bucket; float *esc; float *tab;
    float *inwT; unsigned short *WTbf; float *ppw0T; float *w1T; float *sbf;
    float *h;
    unsigned short *zA; unsigned short *zB;
    float *ssA; float *sdA; float *ssB; float *sdB;
    int N, E, Mtiles;
};

// ---------------- k1: weight prep | node_stats | distance table (independent block ranges) ----------------
__global__ __launch_bounds__(256) void k1_kernel(P p){
    const int PREP_TOTAL = LAYERS*4*64*64 + 65*HID + 2*HID*HID + 2*LAYERS*HEADS; // 77920
    const int CP = (PREP_TOTAL+255)/256;
    const int CN = (p.N+255)/256;
    int bid = blockIdx.x, t = threadIdx.x;
    if (bid < CP){
        int idx = bid*256 + t;
        const int szW = LAYERS*4*64*64;
        const int e1 = szW + 65*HID;
        const int e2 = e1 + HID*HID;
        const int e3 = e2 + HID*HID;
        if (idx < szW){
            p.WTbf[idx] = f2bf(p.proj_w[idx]);
        } else if (idx < e1){
            int r = idx - szW; int i = r/HID, o = r%HID;
            p.inwT[r] = p.inproj_w[o*65 + i];
        } else if (idx < e2){
            int r = idx - e1; int i = r/HID, o = r%HID;
            p.ppw0T[r] = p.ppw[o*HID + i];
        } else if (idx < e3){
            int r = idx - e2; int i = r/HID, o = r%HID;
            p.w1T[r] = p.pw1[o*HID + i];
        } else if (idx < e3 + 2*LAYERS*HEADS){
            int r = idx - e3;
            int hh = r & 3; int type = (r>>2)&1; int l = r>>3;
            const float* a = type ? p.a_dst : p.a_src;
            const float* w = type ? p.w_dst : p.w_src;
            float wh = w[l*16 + hh*4 + 0];
            float s = 0.f;
            for (int c=0;c<16;c++)
                s += a[l*512 + (hh*16+c)*8 + 0] * wh * p.proj_b[l*64 + hh*16 + c];
            p.sbf[r] = s;
        }
    } else if (bid < CP+CN){
        int n = (bid-CP)*256 + t;
        if (n < p.N){
            int g = p.batch[n];
            atomicAdd(&p.possum[g*3+0], p.pos[n*3+0]);
            atomicAdd(&p.possum[g*3+1], p.pos[n*3+1]);
            atomicAdd(&p.possum[g*3+2], p.pos[n*3+2]);
            atomicAdd(&p.pcnt[g], 1.0f);
        }
    } else {
        // distance table: one wave per entry, lane = hidden channel
        int wv = t>>6, lane = t&63;
        int i = (bid-CP-CN)*4 + wv;
        if (i > TABN) return;
        float d = (float)i * (16.0f/TABN);
        float t0 = d * (19.0f/10.0f);
        float hv = p.eb1[lane];
        #pragma unroll
        for (int k=0;k<NRBF;k++){
            float a = t0 - (float)k;
            hv += __expf(-0.5f*a*a) * p.ew1[lane*NRBF+k];
        }
        float act = hv/(1.0f+__expf(-hv));
        float p0 = act*p.ew2[0*HID+lane];
        float p1 = act*p.ew2[1*HID+lane];
        float p2 = act*p.ew2[2*HID+lane];
        float p3 = act*p.ew2[3*HID+lane];
        #pragma unroll
        for (int off=1; off<64; off<<=1){
            p0 += __shfl_xor(p0,off,64);
            p1 += __shfl_xor(p1,off,64);
            p2 += __shfl_xor(p2,off,64);
            p3 += __shfl_xor(p3,off,64);
        }
        if (lane==0){
            *(float4*)&p.tab[(size_t)i*4] = make_float4(p0+p.eb2[0], p1+p.eb2[1],
                                                        p2+p.eb2[2], p3+p.eb2[3]);
        }
    }
}

// ---------------- proj math body (A-frags supplied by caller) ----------------
// valid_rows16: if true all 16 tile rows are this block's nodes; else only rows 0..3 (quad 0).
__device__ __forceinline__ void proj_core(const P& p, int pl, int n0, int nt, int lane,
        const short8* afr, bool rows16,
        unsigned short* zout, float* ssout, float* sdout){
    const unsigned short* WTl = p.WTbf + (size_t)pl*4*64*64;
    const float* pbl = p.proj_b + pl*HID;
    const float* a_src_l = p.a_src + pl*512;
    const float* a_dst_l = p.a_dst + pl*512;
    const float* w_src_l = p.w_src + pl*16;
    const float* w_dst_l = p.w_dst + pl*16;
    const float* sb_l = p.sbf + pl*8;
    int m = lane&15, quad = lane>>4;
    int o = nt*16 + m;
    float cs[4][2][4];
    float pss[4], psd[4];
    #pragma unroll
    for (int r=0;r<4;r++){ pss[r]=0.f; psd[r]=0.f; }
    #pragma unroll
    for (int bp=0; bp<4; bp++){
        const int b0 = 2*bp, b1 = b0+1;
        const int g0 = gradeOf(b0), g1 = gradeOf(b1);
        const short8 w00 = *(const short8*)(WTl + (g0*64 + o)*64 + quad*8);
        const short8 w01 = *(const short8*)(WTl + (g0*64 + o)*64 + 32 + quad*8);
        short8 w10, w11;
        if (g1==g0){ w10 = w00; w11 = w01; }
        else {
            w10 = *(const short8*)(WTl + (g1*64 + o)*64 + quad*8);
            w11 = *(const short8*)(WTl + (g1*64 + o)*64 + 32 + quad*8);
        }
        floatx4 c0 = {0.f,0.f,0.f,0.f}, c1 = {0.f,0.f,0.f,0.f};
        c0 = __builtin_amdgcn_mfma_f32_16x16x32_bf16(afr[4*bp+0], w00, c0, 0,0,0);
        c0 = __builtin_amdgcn_mfma_f32_16x16x32_bf16(afr[4*bp+1], w01, c0, 0,0,0);
        c1 = __builtin_amdgcn_mfma_f32_16x16x32_bf16(afr[4*bp+2], w10, c1, 0,0,0);
        c1 = __builtin_amdgcn_mfma_f32_16x16x32_bf16(afr[4*bp+3], w11, c1, 0,0,0);
        float as0 = a_src_l[o*8+b0]*w_src_l[nt*4+g0];
        float as1 = a_src_l[o*8+b1]*w_src_l[nt*4+g1];
        float ad0 = a_dst_l[o*8+b0]*w_dst_l[nt*4+g0];
        float ad1 = a_dst_l[o*8+b1]*w_dst_l[nt*4+g1];
        float bias0 = (bp==0) ? pbl[o] : 0.0f;
        #pragma unroll
        for (int r=0;r<4;r++){
            float v0 = c0[r], v1 = c1[r];
            pss[r] += v0*as0 + v1*as1;
            psd[r] += v0*ad0 + v1*ad1;
            cs[bp][0][r] = v0 + bias0;
            cs[bp][1][r] = v1;
        }
    }
    #pragma unroll
    for (int r=0;r<4;r++){
        int row = quad*4 + r;
        bool rowok = rows16 ? true : (quad==0);
        int nn = n0 + (rows16 ? row : r);
        if (rowok && nn < p.N){
            unsigned short pk[8];
            #pragma unroll
            for (int bp=0;bp<4;bp++){
                pk[2*bp]   = f2bf(cs[bp][0][r]);
                pk[2*bp+1] = f2bf(cs[bp][1][r]);
            }
            *(int4*)(zout + (size_t)nn*CB + o*8) = *(int4*)pk;
        }
    }
    #pragma unroll
    for (int r=0;r<4;r++){
        float vs = pss[r], vd = psd[r];
        #pragma unroll
        for (int off=1; off<16; off<<=1){
            vs += __shfl_xor(vs, off, 64);
            vd += __shfl_xor(vd, off, 64);
        }
        int row = quad*4 + r;
        bool rowok = rows16 ? true : (quad==0);
        int nn = n0 + (rows16 ? row : r);
        if (m==0 && rowok && nn<p.N){
            ssout[nn*4+nt] = vs + sb_l[nt];
            sdout[nn*4+nt] = vd + sb_l[4+nt];
        }
    }
}

// ---------------- k2: edge-lerp+bucket | embed+proj_0 (independent block ranges) ----------------
__global__ __launch_bounds__(256) void k2_kernel(P p){
    __shared__ unsigned short hAl[8*16*HSTRIDE];
    int t = threadIdx.x, wv = t>>6, lane = t&63;
    if ((int)blockIdx.x >= p.Mtiles){
        int e = ((int)blockIdx.x - p.Mtiles)*256 + t;
        if (e >= p.E) return;
        int s = p.ei[e], d = p.ei[p.E+e];
        float dx = p.pos[s*3+0]-p.pos[d*3+0];
        float dy = p.pos[s*3+1]-p.pos[d*3+1];
        float dz = p.pos[s*3+2]-p.pos[d*3+2];
        float dist = sqrtf(dx*dx+dy*dy+dz*dz);
        float idxf = fminf(dist * ((float)TABN/16.0f), (float)(TABN-1));
        int i0 = (int)idxf;
        float fr = idxf - (float)i0;
        float4 f0 = *(const float4*)&p.tab[(size_t)i0*4];
        float4 f1 = *(const float4*)&p.tab[(size_t)(i0+1)*4];
        *(float4*)&p.esc[(size_t)e*4] = make_float4(
            f0.x + (f1.x-f0.x)*fr, f0.y + (f1.y-f0.y)*fr,
            f0.z + (f1.z-f0.z)*fr, f0.w + (f1.w-f0.w)*fr);
        int slot = atomicAdd(&p.counts[d],1);
        if (slot < CAPB) p.bucket[(size_t)d*CAPB + slot] = e;
        return;
    }
    int n0 = blockIdx.x*16;
    for (int k=0;k<4;k++){
        int m = wv*4 + k;
        int n = n0 + m;
        if (n < p.N){
            int zn = p.zidx[n];                           // wave-uniform
            const float* ar = p.atom_w + (size_t)zn*HID;  // uniform base -> s_load
            float acc = p.inproj_b[lane];
            for (int i=0;i<HID;i++) acc += ar[i] * p.inwT[i*HID + lane];
            int g = p.batch[n];
            float cm = p.pcnt[g]; cm = cm>1.0f?cm:1.0f;
            float px = p.pos[n*3+0]-p.possum[g*3+0]/cm;
            float py = p.pos[n*3+1]-p.possum[g*3+1]/cm;
            float pz = p.pos[n*3+2]-p.possum[g*3+2]/cm;
            float wvv = p.inwT[HID*HID + lane];
            float4* hp = (float4*)&p.h[(size_t)n*CB + lane*8];
            hp[0] = make_float4(acc, wvv*px, wvv*py, wvv*pz);
            hp[1] = make_float4(0.f,0.f,0.f,0.f);
            float vals[8] = {acc, wvv*px, wvv*py, wvv*pz, 0.f,0.f,0.f,0.f};
            #pragma unroll
            for (int b=0;b<8;b++) hAl[(b*16+m)*HSTRIDE + lane] = f2bf(vals[b]);
        } else {
            #pragma unroll
            for (int b=0;b<8;b++) hAl[(b*16+m)*HSTRIDE + lane] = 0;
        }
    }
    __syncthreads();
    int m = lane&15, quad = lane>>4;
    short8 afr[16];
    #pragma unroll
    for (int bp=0;bp<4;bp++){
        int b0=2*bp, b1=b0+1;
        afr[4*bp+0] = *(const short8*)(hAl + (b0*16+m)*HSTRIDE + quad*8);
        afr[4*bp+1] = *(const short8*)(hAl + (b0*16+m)*HSTRIDE + 32 + quad*8);
        afr[4*bp+2] = *(const short8*)(hAl + (b1*16+m)*HSTRIDE + quad*8);
        afr[4*bp+3] = *(const short8*)(hAl + (b1*16+m)*HSTRIDE + 32 + quad*8);
    }
    proj_core(p, 0, n0, wv, lane, afr, true, p.zA, p.ssA, p.sdA);
}

// ---------------- fused agg_l + proj_{l+1} (block = 4 nodes) | last: + prepool ----------------
__global__ __launch_bounds__(256) void aggproj_kernel(P p, int l,
        const unsigned short* __restrict__ zin, const float* __restrict__ ssin,
        const float* __restrict__ sdin, unsigned short* zout, float* ssout, float* sdout,
        int last){
    __shared__ float lw[4][256];
    __shared__ unsigned short hAl[8*4*HSTRIDE];   // 4.3 KB blade-major strip for fused proj
    int wv = threadIdx.x>>6, lane = threadIdx.x&63;
    float* lwv = lw[wv];
    int n0 = blockIdx.x*4;
    int n = n0 + wv;
    bool act = (n < p.N);
    if (act){
        const float* silu_a_l = p.silu_a + l*HID*4;
        const float* silu_b_l = p.silu_b + l*HID*4;
        const float* ln_a_l   = p.ln_a + l*HID;
        int deg = min(p.counts[n], CAPB);
        const int* buck = p.bucket + (size_t)n*CAPB;
        float4 sdl = *(const float4*)&sdin[n*4];
        int h_id = lane>>4;
        float m0=-1e30f,m1=-1e30f,m2=-1e30f,m3=-1e30f;
        float acc[8];
        #pragma unroll
        for (int k=0;k<8;k++) acc[k]=0.f;
        float dn = 0.f;
        for (int c0=0; c0<deg; c0+=64){
            int cnt = min(64, deg-c0);
            int s = 0;
            float l0=-1e30f,l1=-1e30f,l2=-1e30f,l3=-1e30f;
            if (lane < cnt){
                int e = buck[c0+lane]; s = p.ei[e];
                float4 sv = *(const float4*)&ssin[s*4];
                float4 evv = *(const float4*)&p.esc[(size_t)e*4];
                l0 = sv.x+sdl.x+evv.x; l0=(l0>=0.f)?l0:0.2f*l0;
                l1 = sv.y+sdl.y+evv.y; l1=(l1>=0.f)?l1:0.2f*l1;
                l2 = sv.z+sdl.z+evv.z; l2=(l2>=0.f)?l2:0.2f*l2;
                l3 = sv.w+sdl.w+evv.w; l3=(l3>=0.f)?l3:0.2f*l3;
            }
            float c0m=l0,c1m=l1,c2m=l2,c3m=l3;
            #pragma unroll
            for (int off=1; off<64; off<<=1){
                c0m=fmaxf(c0m,__shfl_xor(c0m,off,64));
                c1m=fmaxf(c1m,__shfl_xor(c1m,off,64));
                c2m=fmaxf(c2m,__shfl_xor(c2m,off,64));
                c3m=fmaxf(c3m,__shfl_xor(c3m,off,64));
            }
            float nm0=fmaxf(m0,c0m), nm1=fmaxf(m1,c1m), nm2=fmaxf(m2,c2m), nm3=fmaxf(m3,c3m);
            float mo  = (h_id==0)?m0:((h_id==1)?m1:((h_id==2)?m2:m3));
            float nmo = (h_id==0)?nm0:((h_id==1)?nm1:((h_id==2)?nm2:nm3));
            float sc = __expf(mo-nmo);
            #pragma unroll
            for (int k=0;k<8;k++) acc[k]*=sc;
            dn *= sc;
            m0=nm0; m1=nm1; m2=nm2; m3=nm3;
            float4 wquad = make_float4(__expf(l0-nm0),__expf(l1-nm1),__expf(l2-nm2),__expf(l3-nm3));
            *(float4*)&lwv[lane*4] = wquad;
            int rc = (cnt+3)&~3;
            for (int j=0;j<rc;j+=4){
                int s0 = __shfl(s, j+0), s1 = __shfl(s, j+1);
                int s2 = __shfl(s, j+2), s3 = __shfl(s, j+3);
                const int4 zv0 = *((const int4*)(zin + (size_t)s0*CB) + lane);
                const int4 zv1 = *((const int4*)(zin + (size_t)s1*CB) + lane);
                const int4 zv2 = *((const int4*)(zin + (size_t)s2*CB) + lane);
                const int4 zv3 = *((const int4*)(zin + (size_t)s3*CB) + lane);
                float w0 = lwv[(j+0)*4 + h_id], w1 = lwv[(j+1)*4 + h_id];
                float w2 = lwv[(j+2)*4 + h_id], w3 = lwv[(j+3)*4 + h_id];
                acc[0] += w0*bflo(zv0.x); acc[1] += w0*bfhi(zv0.x);
                acc[2] += w0*bflo(zv0.y); acc[3] += w0*bfhi(zv0.y);
                acc[4] += w0*bflo(zv0.z); acc[5] += w0*bfhi(zv0.z);
                acc[6] += w0*bflo(zv0.w); acc[7] += w0*bfhi(zv0.w);
                acc[0] += w1*bflo(zv1.x); acc[1] += w1*bfhi(zv1.x);
                acc[2] += w1*bflo(zv1.y); acc[3] += w1*bfhi(zv1.y);
                acc[4] += w1*bflo(zv1.z); acc[5] += w1*bfhi(zv1.z);
                acc[6] += w1*bflo(zv1.w); acc[7] += w1*bfhi(zv1.w);
                acc[0] += w2*bflo(zv2.x); acc[1] += w2*bfhi(zv2.x);
                acc[2] += w2*bflo(zv2.y); acc[3] += w2*bfhi(zv2.y);
                acc[4] += w2*bflo(zv2.z); acc[5] += w2*bfhi(zv2.z);
                acc[6] += w2*bflo(zv2.w); acc[7] += w2*bfhi(zv2.w);
                acc[0] += w3*bflo(zv3.x); acc[1] += w3*bfhi(zv3.x);
                acc[2] += w3*bflo(zv3.y); acc[3] += w3*bfhi(zv3.y);
                acc[4] += w3*bflo(zv3.z); acc[5] += w3*bfhi(zv3.z);
                acc[6] += w3*bflo(zv3.w); acc[7] += w3*bfhi(zv3.w);
                dn += w0+w1+w2+w3;
            }
        }
        float inv = 1.0f/(dn + 1e-16f);
        float x[8];
        #pragma unroll
        for (int k=0;k<8;k++) x[k] = acc[k]*inv;
        float4 sa = *(const float4*)&silu_a_l[lane*4];
        float4 sb = *(const float4*)&silu_b_l[lane*4];
        float n1 = x[1]*x[1]+x[2]*x[2]+x[3]*x[3];
        float n2 = x[4]*x[4]+x[5]*x[5]+x[6]*x[6];
        float n3 = x[7]*x[7];
        float g0 = 1.0f/(1.0f+__expf(-(sa.x*x[0]+sb.x)));
        float g1 = 1.0f/(1.0f+__expf(-(sa.y*n1+sb.y)));
        float g2 = 1.0f/(1.0f+__expf(-(sa.z*n2+sb.z)));
        float g3 = 1.0f/(1.0f+__expf(-(sa.w*n3+sb.w)));
        float4 r0 = *(const float4*)&p.h[(size_t)n*CB + lane*8];
        float4 r1 = *(const float4*)&p.h[(size_t)n*CB + lane*8 + 4];
        float val[8];
        val[0]=g0*x[0]+r0.x; val[1]=g1*x[1]+r0.y; val[2]=g1*x[2]+r0.z; val[3]=g1*x[3]+r0.w;
        val[4]=g2*x[4]+r1.x; val[5]=g2*x[5]+r1.y; val[6]=g2*x[6]+r1.z; val[7]=g3*x[7]+r1.w;
        float ss=0.f;
        #pragma unroll
        for (int k=0;k<8;k++) ss += val[k]*val[k];
        float nr = sqrtf(ss);
        #pragma unroll
        for (int off=1; off<64; off<<=1) nr += __shfl_xor(nr, off, 64);
        float mean = nr*(1.0f/64.0f) + 1e-6f;
        float scale = p.ln_a[l*HID + lane]/mean;
        float outv[8];
        #pragma unroll
        for (int k=0;k<8;k++) outv[k] = scale*val[k];
        if (!last){
            *(float4*)&p.h[(size_t)n*CB + lane*8]     = make_float4(outv[0],outv[1],outv[2],outv[3]);
            *(float4*)&p.h[(size_t)n*CB + lane*8 + 4] = make_float4(outv[4],outv[5],outv[6],outv[7]);
            #pragma unroll
            for (int b=0;b<8;b++) hAl[(b*4+wv)*HSTRIDE + lane] = f2bf(outv[b]);
        } else {
            float x0 = outv[0];
            float accp = p.ppb[lane];
            for (int i=0;i<HID;i++) accp += __shfl(x0, i, 64) * p.ppw0T[i*HID + lane];
            atomicAdd(&p.gbuf[p.batch[n]*HID + lane], accp);
        }
    } else if (!last){
        #pragma unroll
        for (int b=0;b<8;b++) hAl[(b*4+wv)*HSTRIDE + lane] = 0;
    }
    if (!last){
        __syncthreads();
        // fused proj_{l+1} for this block's 4 nodes; MFMA tile rows 4..15 are duplicates, discarded
        int m = lane&15, quad = lane>>4;
        int mm = m&3;
        short8 afr[16];
        #pragma unroll
        for (int bp=0;bp<4;bp++){
            int b0=2*bp, b1=b0+1;
            afr[4*bp+0] = *(const short8*)(hAl + (b0*4+mm)*HSTRIDE + quad*8);
            afr[4*bp+1] = *(const short8*)(hAl + (b0*4+mm)*HSTRIDE + 32 + quad*8);
            afr[4*bp+2] = *(const short8*)(hAl + (b1*4+mm)*HSTRIDE + quad*8);
            afr[4*bp+3] = *(const short8*)(hAl + (b1*4+mm)*HSTRIDE + 32 + quad*8);
        }
        proj_core(p, l+1, n0, wv, lane, afr, false, zout, ssout, sdout);
    }
}

// ---------------- final readout ----------------
__global__ void final_kernel(P p){
    int gid = blockIdx.x; int o = threadIdx.x;  // 64 threads = 1 wave
    float gv = p.gbuf[gid*HID + o];
    float a = p.pb1[o];
    for (int i=0;i<HID;i++) a += __shfl(gv, i, 64) * p.w1T[i*HID + o];
    float act = a/(1.0f+__expf(-a));
    float pv = act * p.pw2[o];
    #pragma unroll
    for (int off=1; off<64; off<<=1) pv += __shfl_xor(pv, off, 64);
    if (o==0) p.out[gid] = pv + p.pb2[0];
}

extern "C" void kernel_launch(void* const* d_in, const int* in_sizes, int n_in,
                              void* d_out, int out_size, void* d_ws, size_t ws_size,
                              hipStream_t stream) {
    P p;
    p.pos      = (const float*)d_in[0];
    p.zidx     = (const int*)  d_in[1];
    p.ei       = (const int*)  d_in[2];
    p.batch    = (const int*)  d_in[3];
    p.atom_w   = (const float*)d_in[4];
    p.inproj_w = (const float*)d_in[5];
    p.inproj_b = (const float*)d_in[6];
    p.ew1      = (const float*)d_in[7];
    p.eb1      = (const float*)d_in[8];
    p.ew2      = (const float*)d_in[9];
    p.eb2      = (const float*)d_in[10];
    p.proj_w   = (const float*)d_in[11];
    p.proj_b   = (const float*)d_in[12];
    p.a_src    = (const float*)d_in[13];
    p.a_dst    = (const float*)d_in[14];
    p.w_src    = (const float*)d_in[15];
    p.w_dst    = (const float*)d_in[16];
    p.ln_a     = (const float*)d_in[17];
    p.silu_a   = (const float*)d_in[18];
    p.silu_b   = (const float*)d_in[19];
    p.ppw      = (const float*)d_in[20];
    p.ppb      = (const float*)d_in[21];
    p.pw1      = (const float*)d_in[22];
    p.pb1      = (const float*)d_in[23];
    p.pw2      = (const float*)d_in[24];
    p.pb2      = (const float*)d_in[25];
    p.out = (float*)d_out;

    const int N = in_sizes[0]/3;
    const int E = in_sizes[2]/2;
    p.N = N; p.E = E; p.Mtiles = (N+15)/16;

    float* wsf = (float*)d_ws;
    size_t off = 0;
    auto alloc = [&](size_t nelem){ size_t r = off; off += (nelem + 63) & ~(size_t)63; return r; };
    size_t o_counts = alloc(N);          // int
    size_t o_possum = alloc(NG*3);
    size_t o_pcnt   = alloc(NG);
    size_t o_g      = alloc(NG*HID);
    size_t zero_end = off;
    size_t o_bucket = alloc((size_t)N*CAPB);   // int
    size_t o_esc    = alloc((size_t)E*4);
    size_t o_tab    = alloc((size_t)(TABN+2)*4);
    size_t o_ssA    = alloc((size_t)N*4);
    size_t o_sdA    = alloc((size_t)N*4);
    size_t o_ssB    = alloc((size_t)N*4);
    size_t o_sdB    = alloc((size_t)N*4);
    size_t o_inwT   = alloc(65*HID);
    size_t o_WTbf   = alloc((size_t)LAYERS*4*64*64/2);   // ushort
    size_t o_ppw0T  = alloc(HID*HID);
    size_t o_w1T    = alloc(HID*HID);
    size_t o_sbf    = alloc(2*LAYERS*HEADS);
    size_t o_h      = alloc((size_t)N*CB);
    size_t o_zA     = alloc((size_t)N*CB/2);             // ushort
    size_t o_zB     = alloc((size_t)N*CB/2);             // ushort

    p.counts = (int*)(wsf + o_counts);
    p.possum = wsf + o_possum;
    p.pcnt   = wsf + o_pcnt;
    p.gbuf   = wsf + o_g;
    p.bucket = (int*)(wsf + o_bucket);
    p.esc    = wsf + o_esc;
    p.tab    = wsf + o_tab;
    p.ssA    = wsf + o_ssA;
    p.sdA    = wsf + o_sdA;
    p.ssB    = wsf + o_ssB;
    p.sdB    = wsf + o_sdB;
    p.inwT   = wsf + o_inwT;
    p.WTbf   = (unsigned short*)(wsf + o_WTbf);
    p.ppw0T  = wsf + o_ppw0T;
    p.w1T    = wsf + o_w1T;
    p.sbf    = wsf + o_sbf;
    p.h      = wsf + o_h;
    p.zA     = (unsigned short*)(wsf + o_zA);
    p.zB     = (unsigned short*)(wsf + o_zB);

    hipMemsetAsync(wsf, 0, zero_end*sizeof(float), stream);

    const int PREP_TOTAL = LAYERS*4*64*64 + 65*HID + 2*HID*HID + 2*LAYERS*HEADS;
    const int CP = (PREP_TOTAL+255)/256;
    const int CN = (N+255)/256;
    const int CE = (E+255)/256;
    const int CT = (TABN+1+3)/4;

    k1_kernel<<<CP+CN+CT, 256, 0, stream>>>(p);
    k2_kernel<<<p.Mtiles + CE, 256, 0, stream>>>(p);            // -> esc/bucket | zA, ssA, sdA, h

    aggproj_kernel<<<(N+3)/4, 256, 0, stream>>>(p, 0, p.zA, p.ssA, p.sdA, p.zB, p.ssB, p.sdB, 0);
    aggproj_kernel<<<(N+3)/4, 256, 0, stream>>>(p, 1, p.zB, p.ssB, p.sdB, p.zA, p.ssA, p.sdA, 0);
    aggproj_kernel<<<(N+3)/4, 256, 0, stream>>>(p, 2, p.zA, p.ssA, p.sdA, p.zB, p.ssB, p.sdB, 0);
    aggproj_kernel<<<(N+3)/4, 256, 0, stream>>>(p, 3, p.zB, p.ssB, p.sdB, p.zA, p.ssA, p.sdA, 1);

    final_kernel<<<NG, 64, 0, stream>>>(p);
}